// Round 6
// baseline (181.447 us; speedup 1.0000x reference)
//
#include <hip/hip_runtime.h>
#include <math.h>

// B=1, I=J=256, C=128, H=4, CH=32
#define NI 256
#define NJ 256
#define NC 128
#define NH 4
#define NCH 32
#define LOG2E 1.4426950408889634f

typedef _Float16 f16x8 __attribute__((ext_vector_type(8)));
typedef unsigned short u16x8 __attribute__((ext_vector_type(8)));
typedef unsigned int u32x4 __attribute__((ext_vector_type(4)));
typedef float f32x16 __attribute__((ext_vector_type(16)));

__device__ __forceinline__ unsigned short f2h(float f) {
    return __builtin_bit_cast(unsigned short, (_Float16)f);
}
__device__ __forceinline__ unsigned pkrtz(float a, float b) {
    return __builtin_bit_cast(unsigned, __builtin_amdgcn_cvt_pkrtz(a, b));
}
__device__ __forceinline__ f32x16 fzero16() {
    f32x16 z;
#pragma unroll
    for (int r = 0; r < 16; ++r) z[r] = 0.f;
    return z;
}
__device__ __forceinline__ f32x16 mfma16f(f16x8 a, f16x8 b, f32x16 c) {
    return __builtin_amdgcn_mfma_f32_32x32x16_f16(a, b, c, 0, 0, 0);
}

// ---------------------------------------------------------------------------
// Kernel 0: transpose+convert weights to f16.
// ---------------------------------------------------------------------------
__global__ __launch_bounds__(256) void convert_weights(
    const float* __restrict__ wq, const float* __restrict__ wk,
    const float* __restrict__ wv, const float* __restrict__ wg,
    const float* __restrict__ wo, const float* __restrict__ w_tri,
    unsigned short* __restrict__ Wt_all, unsigned short* __restrict__ Wto,
    unsigned short* __restrict__ Wtri_pad)
{
    int id = blockIdx.x * 256 + threadIdx.x;          // 0..86015
    if (id < 4 * 16384) {
        int m = id >> 14, r = id & 16383;
        int kk = r >> 7, c = r & 127;
        const float* W = (m == 0) ? wq : (m == 1) ? wk : (m == 2) ? wv : wg;
        Wt_all[(m * 128 + c) * 128 + kk] = f2h(W[kk * 128 + c]);
    } else if (id < 5 * 16384) {
        int r = id - 4 * 16384;
        int kk = r >> 7, c = r & 127;
        Wto[c * 128 + kk] = f2h(wo[kk * 128 + c]);
    } else {
        int r = id - 5 * 16384;                        // 0..4095
        int col = r >> 7, kk = r & 127;
        Wtri_pad[col * 128 + kk] = (col < NH) ? f2h(w_tri[kk * NH + col]) : (unsigned short)0;
    }
}

// ---------------------------------------------------------------------------
// Kernel 1: LayerNorm + MFMA projections (q,k,v,g f16) + tri bias via MFMA.
// Block = 64 tokens, 256 threads. q pre-scaled by CH^-0.5 * log2(e).
// Epilogue: fragments staged through LDS -> fully coalesced b128 stores.
// ---------------------------------------------------------------------------
#define XNP 136
__global__ __launch_bounds__(256, 2) void ln_proj_mfma(
    const float* __restrict__ x, const float* __restrict__ ln_w, const float* __restrict__ ln_b,
    const unsigned short* __restrict__ Wt_all, const unsigned short* __restrict__ Wtri_pad,
    const float* __restrict__ bg,
    unsigned short* __restrict__ q, unsigned short* __restrict__ k,
    unsigned short* __restrict__ v, unsigned short* __restrict__ g,
    float* __restrict__ tri)
{
    __shared__ unsigned short xn[64 * XNP];   // ~17.4 KB, reused by epilogue
    const int tid = threadIdx.x;
    const long tok0 = (long)blockIdx.x * 64;

    const int lane8 = tid & 7;
#pragma unroll
    for (int p = 0; p < 2; ++p) {
        const int t = p * 32 + (tid >> 3);
        const float4* xrow = (const float4*)(x + (tok0 + t) * NC + lane8 * 16);
        float4 xv[4];
        float s = 0.f;
#pragma unroll
        for (int u = 0; u < 4; ++u) {
            xv[u] = xrow[u];
            s += xv[u].x + xv[u].y + xv[u].z + xv[u].w;
        }
#pragma unroll
        for (int off = 4; off; off >>= 1) s += __shfl_down(s, off, 8);
        const float mu = __shfl(s, 0, 8) * (1.f / (float)NC);
        float s2 = 0.f;
#pragma unroll
        for (int u = 0; u < 4; ++u) {
            float dx;
            dx = xv[u].x - mu; s2 += dx * dx;
            dx = xv[u].y - mu; s2 += dx * dx;
            dx = xv[u].z - mu; s2 += dx * dx;
            dx = xv[u].w - mu; s2 += dx * dx;
        }
#pragma unroll
        for (int off = 4; off; off >>= 1) s2 += __shfl_down(s2, off, 8);
        const float rstd = rsqrtf(__shfl(s2, 0, 8) * (1.f / (float)NC) + 1e-5f);
#pragma unroll
        for (int u = 0; u < 4; ++u) {
            const int c = lane8 * 16 + u * 4;
            const float4 lw = *(const float4*)(ln_w + c);
            const float4 lb = *(const float4*)(ln_b + c);
            float o0 = (xv[u].x - mu) * rstd * lw.x + lb.x;
            float o1 = (xv[u].y - mu) * rstd * lw.y + lb.y;
            float o2 = (xv[u].z - mu) * rstd * lw.z + lb.z;
            float o3 = (xv[u].w - mu) * rstd * lw.w + lb.w;
            *(unsigned*)&xn[t * XNP + c]     = pkrtz(o0, o1);
            *(unsigned*)&xn[t * XNP + c + 2] = pkrtz(o2, o3);
        }
    }
    __syncthreads();

    const int w = tid >> 6, L = tid & 63, lh = L >> 5, lc = L & 31;
    f32x16 acc[2][4], accT[2];
#pragma unroll
    for (int mt = 0; mt < 2; ++mt) {
        accT[mt] = fzero16();
#pragma unroll
        for (int nt = 0; nt < 4; ++nt) acc[mt][nt] = fzero16();
    }

#pragma unroll
    for (int k0 = 0; k0 < 8; ++k0) {
        f16x8 a0 = *(const f16x8*)&xn[(lc)      * XNP + k0 * 16 + lh * 8];
        f16x8 a1 = *(const f16x8*)&xn[(32 + lc) * XNP + k0 * 16 + lh * 8];
#pragma unroll
        for (int nt = 0; nt < 4; ++nt) {
            const int ntile = w + 4 * nt;
            f16x8 b = *(const f16x8*)&Wt_all[(ntile * 32 + lc) * 128 + k0 * 16 + lh * 8];
            acc[0][nt] = mfma16f(a0, b, acc[0][nt]);
            acc[1][nt] = mfma16f(a1, b, acc[1][nt]);
        }
        f16x8 bt = *(const f16x8*)&Wtri_pad[lc * 128 + k0 * 16 + lh * 8];
        accT[0] = mfma16f(a0, bt, accT[0]);
        accT[1] = mfma16f(a1, bt, accT[1]);
    }

    const int a_row = (int)(tok0 >> 8);
    const int b0    = (int)(tok0 & 255);
    int rowl[16];
#pragma unroll
    for (int r = 0; r < 16; ++r) rowl[r] = (r & 3) + 8 * (r >> 2) + 4 * lh;

    // tri (fp32, un-scaled; swizzle kernel applies log2e)
    if (lc < NH) {
        float* tb = tri + ((long)lc * NI + a_row) * NJ + b0;
#pragma unroll
        for (int mt = 0; mt < 2; ++mt)
#pragma unroll
            for (int r = 0; r < 16; ++r)
                tb[mt * 32 + rowl[r]] = accT[mt][r];
    }

    // q,k,v,g epilogue: LDS-staged, coalesced 16B stores
    const float bgv = bg[w * 32 + lc];
    const int token = tid >> 2, c8 = (tid & 3) * 8;
#pragma unroll
    for (int m = 0; m < 4; ++m) {
        __syncthreads();                      // prior xn reads / prior coop reads done
#pragma unroll
        for (int mt = 0; mt < 2; ++mt) {
#pragma unroll
            for (int r = 0; r < 16; ++r) {
                const int row = mt * 32 + rowl[r];
                float val = acc[mt][m][r];
                if (m == 0) val *= 0.25503486f;  // CH^-0.5 * log2(e)
                if (m == 3) val = __builtin_amdgcn_rcpf(1.f + __builtin_amdgcn_exp2f(-LOG2E * (val + bgv)));
                xn[row * XNP + w * 32 + lc] = f2h(val);
            }
        }
        __syncthreads();
        unsigned short* O = (m == 0) ? q : (m == 1) ? k : (m == 2) ? v : g;
#pragma unroll
        for (int hh = 0; hh < 4; ++hh) {
            const u16x8 vec = *(const u16x8*)&xn[token * XNP + hh * 32 + c8];
            *(u16x8*)(O + (((long)a_row * NH + hh) * NJ + b0 + token) * NCH + c8) = vec;
        }
    }
}

// ---------------------------------------------------------------------------
// Kernel 1b: swizzle tri into S^T C-fragment order, scaled by log2(e).
// Grid (H, 8, 8) = 256 blocks, 64 threads.
// ---------------------------------------------------------------------------
__global__ __launch_bounds__(64) void swizzle_triT(
    const float* __restrict__ tri, float* __restrict__ tswz)
{
    __shared__ float Ls[32 * 36];
    const int h = blockIdx.x, qt = blockIdx.y, kt = blockIdx.z;
    const int l = threadIdx.x;
#pragma unroll
    for (int rr = 0; rr < 4; ++rr) {
        const int fi = rr * 64 + l;           // 0..255 float4s
        const int row = fi >> 3, c4 = fi & 7;
        *(float4*)&Ls[row * 36 + c4 * 4] =
            *(const float4*)(tri + ((long)h * NI + qt * 32 + row) * NJ + kt * 32 + c4 * 4);
    }
    __syncthreads();
    const int lc = l & 31, lhh = l >> 5;
    float* dst = tswz + (((long)(h * 8 + qt) * 8 + kt) * 64 + l) * 16;
    float vals[16];
#pragma unroll
    for (int r = 0; r < 16; ++r)
        vals[r] = LOG2E * Ls[lc * 36 + kt * 0 + (r & 3) + 8 * (r >> 2) + 4 * lhh];
#pragma unroll
    for (int u = 0; u < 4; ++u)
        *(float4*)(dst + u * 4) = make_float4(vals[4*u], vals[4*u+1], vals[4*u+2], vals[4*u+3]);
}

// ---------------------------------------------------------------------------
// Kernel 2: fused attention + gating + output projection, split-K.
// Block = (i, qh): 128 queries, 512 threads (8 waves).
// Wave w: q-tile qh*4+(w&3); key half (w>>2). Partial O/ls merged via LDS;
// Wo ct-tiles split across wave pairs. tri enters as MFMA C-initializer.
// ---------------------------------------------------------------------------
#define KSP 40
#define VTP 264
#define QSP 40
#define GSP 40
__global__ __launch_bounds__(512, 4) void attn_fused(
    const unsigned short* __restrict__ q, const unsigned short* __restrict__ k,
    const unsigned short* __restrict__ v, const unsigned short* __restrict__ g,
    const float* __restrict__ tswz, const float* __restrict__ mask,
    const unsigned short* __restrict__ Wto, const float* __restrict__ bo,
    float* __restrict__ out)
{
    __shared__ char smem[79360];
    unsigned short* Ks = (unsigned short*)(smem);            // 20480
    unsigned short* Vt = (unsigned short*)(smem + 20480);    // 16896
    unsigned short* Qs = (unsigned short*)(smem + 37376);    // 10240
    unsigned short* Gs = (unsigned short*)(smem + 47616);    // 10240
    float*       maskb = (float*)(smem + 57856);             // 1024
    float*         mrg = (float*)(smem + 58880);             // 4*64*20*4 = 20480

    const int i = blockIdx.x, qh = blockIdx.y;
    const int tid = threadIdx.x;
    const int w = tid >> 6, L = tid & 63, lh = L >> 5, lc = L & 31;
    const int wq4 = w & 3, ku = w >> 2;
    const int qt = qh * 4 + wq4;
    const int tb0 = ku * 4;

    if (tid < 256) maskb[tid] = (LOG2E * 1.0e9f) * (mask[i * NJ + tid] - 1.0f);

    int rowl[16];
#pragma unroll
    for (int r = 0; r < 16; ++r) rowl[r] = (r & 3) + 8 * (r >> 2) + 4 * lh;

    f32x16 outacc[2];
    outacc[0] = fzero16(); outacc[1] = fzero16();
    float* myMrg = mrg + ((long)wq4 * 64 + L) * 20;

    for (int h = 0; h < NH; ++h) {
        const long base = ((long)i * NH + h) * NJ * NCH;
        // ---- stage K (2 b128/thread) ----
#pragma unroll
        for (int it = 0; it < 2; ++it) {
            const int idx = it * 512 + tid;
            const int key = idx >> 2, c8 = (idx & 3) * 8;
            *(u16x8*)&Ks[key * KSP + c8] = *(const u16x8*)(k + base + key * NCH + c8);
        }
        // ---- stage Q, G (1 b128 each) ----
        {
            const int row = tid >> 2, c8 = (tid & 3) * 8;
            *(u16x8*)&Qs[row * QSP + c8] = *(const u16x8*)(q + base + (qh * 128 + row) * NCH + c8);
            *(u16x8*)&Gs[row * GSP + c8] = *(const u16x8*)(g + base + (qh * 128 + row) * NCH + c8);
        }
        // ---- stage V transposed ----
        {
            const int key = tid >> 1, hf = tid & 1;
            const u16x8 r0 = *(const u16x8*)(v + base + key * NCH + hf * 16);
            const u16x8 r1 = *(const u16x8*)(v + base + key * NCH + hf * 16 + 8);
#pragma unroll
            for (int u = 0; u < 8; ++u) {
                Vt[(hf * 16 + u)     * VTP + key] = r0[u];
                Vt[(hf * 16 + 8 + u) * VTP + key] = r1[u];
            }
        }
        __syncthreads();

        const f16x8 a0 = *(const f16x8*)&Qs[(wq4 * 32 + lc) * QSP + lh * 8];
        const f16x8 a1 = *(const f16x8*)&Qs[(wq4 * 32 + lc) * QSP + 16 + lh * 8];

        float ls = 0.f;
        f32x16 O = fzero16();

#pragma unroll
        for (int tt = 0; tt < 4; ++tt) {
            const int t = tb0 + tt;
            // S^T = K·Q + tri (C-initializer!)
            const float* tv = tswz + (((long)(h * 8 + qt)) * 8 + t) * 1024 + (long)L * 16;
            f32x16 s;
#pragma unroll
            for (int u = 0; u < 4; ++u) {
                const float4 t4 = *(const float4*)(tv + u * 4);
                s[4*u] = t4.x; s[4*u+1] = t4.y; s[4*u+2] = t4.z; s[4*u+3] = t4.w;
            }
            const f16x8 kb0 = *(const f16x8*)&Ks[(t * 32 + lc) * KSP + lh * 8];
            const f16x8 kb1 = *(const f16x8*)&Ks[(t * 32 + lc) * KSP + 16 + lh * 8];
            s = mfma16f(kb0, a0, s);
            s = mfma16f(kb1, a1, s);

            unsigned pk[8];
#pragma unroll
            for (int gg = 0; gg < 4; ++gg) {
                const float4 mb = *(const float4*)&maskb[t * 32 + gg * 8 + 4 * lh];
                const float p0 = __builtin_amdgcn_exp2f(fminf(s[4*gg+0] + mb.x, 15.f));
                const float p1 = __builtin_amdgcn_exp2f(fminf(s[4*gg+1] + mb.y, 15.f));
                const float p2 = __builtin_amdgcn_exp2f(fminf(s[4*gg+2] + mb.z, 15.f));
                const float p3 = __builtin_amdgcn_exp2f(fminf(s[4*gg+3] + mb.w, 15.f));
                ls += (p0 + p1) + (p2 + p3);
                pk[2*gg]   = pkrtz(p0, p1);
                pk[2*gg+1] = pkrtz(p2, p3);
            }
            // O^T += V^T @ P^T (in-register B-frag via lane^32 exchange)
#pragma unroll
            for (int ss = 0; ss < 2; ++ss) {
                const unsigned give0 = lh ? pk[4*ss]   : pk[4*ss+2];
                const unsigned give1 = lh ? pk[4*ss+1] : pk[4*ss+3];
                const unsigned t0 = __shfl_xor(give0, 32);
                const unsigned t1 = __shfl_xor(give1, 32);
                u32x4 bw;
                bw[0] = lh ? t0 : pk[4*ss];
                bw[1] = lh ? t1 : pk[4*ss+1];
                bw[2] = lh ? pk[4*ss+2] : t0;
                bw[3] = lh ? pk[4*ss+3] : t1;
                const f16x8 pb = __builtin_bit_cast(f16x8, bw);
                const f16x8 va = *(const f16x8*)&Vt[lc * VTP + t * 32 + ss * 16 + lh * 8];
                O = mfma16f(va, pb, O);
            }
        }

        // ---- merge key halves ----
        if (ku) {
#pragma unroll
            for (int u = 0; u < 4; ++u)
                *(float4*)(myMrg + u * 4) = make_float4(O[4*u], O[4*u+1], O[4*u+2], O[4*u+3]);
            myMrg[16] = ls;
        }
        __syncthreads();
        if (!ku) {
#pragma unroll
            for (int u = 0; u < 4; ++u) {
                const float4 p4 = *(const float4*)(myMrg + u * 4);
                O[4*u] += p4.x; O[4*u+1] += p4.y; O[4*u+2] += p4.z; O[4*u+3] += p4.w;
            }
            ls += myMrg[16];
            ls += __shfl_xor(ls, 32);
            const float rl = __builtin_amdgcn_rcpf(ls);
            unsigned pg[8];
#pragma unroll
            for (int gg = 0; gg < 4; ++gg) {
                const unsigned short* gp = &Gs[(wq4 * 32 + lc) * GSP + gg * 8 + 4 * lh];
                const float o0 = O[4*gg+0] * rl * (float)*(const _Float16*)&gp[0];
                const float o1 = O[4*gg+1] * rl * (float)*(const _Float16*)&gp[1];
                const float o2 = O[4*gg+2] * rl * (float)*(const _Float16*)&gp[2];
                const float o3 = O[4*gg+3] * rl * (float)*(const _Float16*)&gp[3];
                pg[2*gg]   = pkrtz(o0, o1);
                pg[2*gg+1] = pkrtz(o2, o3);
            }
            unsigned obw[8];
#pragma unroll
            for (int ss = 0; ss < 2; ++ss) {
                const unsigned give0 = lh ? pg[4*ss]   : pg[4*ss+2];
                const unsigned give1 = lh ? pg[4*ss+1] : pg[4*ss+3];
                const unsigned t0 = __shfl_xor(give0, 32);
                const unsigned t1 = __shfl_xor(give1, 32);
                obw[4*ss+0] = lh ? t0 : pg[4*ss];
                obw[4*ss+1] = lh ? t1 : pg[4*ss+1];
                obw[4*ss+2] = lh ? pg[4*ss+2] : t0;
                obw[4*ss+3] = lh ? pg[4*ss+3] : t1;
            }
            u32x4 w0, w1;
#pragma unroll
            for (int u = 0; u < 4; ++u) { w0[u] = obw[u]; w1[u] = obw[4+u]; }
            ((u32x4*)myMrg)[0] = w0;
            ((u32x4*)myMrg)[1] = w1;
        }
        __syncthreads();
        // ---- out^T += Wo^T @ OG^T (ct tiles split across wave pairs) ----
        {
            const u32x4 b0v = ((const u32x4*)myMrg)[0];
            const u32x4 b1v = ((const u32x4*)myMrg)[1];
#pragma unroll
            for (int ss = 0; ss < 2; ++ss) {
                const f16x8 ogf = __builtin_bit_cast(f16x8, ss ? b1v : b0v);
#pragma unroll
                for (int c2 = 0; c2 < 2; ++c2) {
                    const f16x8 wa = *(const f16x8*)(Wto + ((ku * 2 + c2) * 32 + lc) * NC
                                                     + h * NCH + ss * 16 + lh * 8);
                    outacc[c2] = mfma16f(wa, ogf, outacc[c2]);
                }
            }
        }
    }

    // ---- epilogue: stage out^T tiles through LDS, coalesced float4 stores ----
    float* outs = (float*)smem;               // 128*68*4 = 34816 B
#pragma unroll
    for (int ph = 0; ph < 2; ++ph) {
        __syncthreads();
        if (ku == ph) {
#pragma unroll
            for (int c2 = 0; c2 < 2; ++c2)
#pragma unroll
                for (int r = 0; r < 16; ++r)
                    outs[(wq4 * 32 + lc) * 68 + c2 * 32 + rowl[r]] = outacc[c2][r];
        }
        __syncthreads();
#pragma unroll
        for (int it = 0; it < 4; ++it) {
            const int fi = it * 512 + tid;    // 0..2047
            const int qrow = fi >> 4, c4 = fi & 15;
            const float4 vv = *(const float4*)&outs[qrow * 68 + c4 * 4];
            const float4 b4 = *(const float4*)(bo + ph * 64 + c4 * 4);
            float4 st;
            st.x = vv.x + b4.x; st.y = vv.y + b4.y;
            st.z = vv.z + b4.z; st.w = vv.w + b4.w;
            *(float4*)(out + ((long)i * NJ + qh * 128 + qrow) * NC + ph * 64 + c4 * 4) = st;
        }
    }
}

// ---------------------------------------------------------------------------
extern "C" void kernel_launch(void* const* d_in, const int* in_sizes, int n_in,
                              void* d_out, int out_size, void* d_ws, size_t ws_size,
                              hipStream_t stream) {
    const float* x     = (const float*)d_in[0];
    const float* mask  = (const float*)d_in[1];
    const float* ln_w  = (const float*)d_in[3];
    const float* ln_b  = (const float*)d_in[4];
    const float* w_tri = (const float*)d_in[5];
    const float* wq    = (const float*)d_in[6];
    const float* wk    = (const float*)d_in[7];
    const float* wv    = (const float*)d_in[8];
    const float* wg    = (const float*)d_in[9];
    const float* bg    = (const float*)d_in[10];
    const float* wo    = (const float*)d_in[11];
    const float* bo    = (const float*)d_in[12];
    float* out = (float*)d_out;

    char* p = (char*)d_ws;
    const long TOK = (long)NI * NJ;                     // 65536
    const long QB  = TOK * NC * sizeof(unsigned short); // 16.78 MB
    unsigned short* q  = (unsigned short*)p; p += QB;
    unsigned short* k  = (unsigned short*)p; p += QB;
    unsigned short* v  = (unsigned short*)p; p += QB;
    unsigned short* g  = (unsigned short*)p; p += QB;
    float* tri  = (float*)p; p += (long)NH * NI * NJ * sizeof(float);
    float* tswz = (float*)p; p += (long)NH * NI * NJ * sizeof(float);
    unsigned short* Wt_all   = (unsigned short*)p; p += 4 * 128 * 128 * sizeof(unsigned short);
    unsigned short* Wto      = (unsigned short*)p; p += 128 * 128 * sizeof(unsigned short);
    unsigned short* Wtri_pad = (unsigned short*)p; p += 32 * 128 * sizeof(unsigned short);

    hipLaunchKernelGGL(convert_weights, dim3(336), dim3(256), 0, stream,
                       wq, wk, wv, wg, wo, w_tri, Wt_all, Wto, Wtri_pad);
    hipLaunchKernelGGL(ln_proj_mfma, dim3(TOK / 64), dim3(256), 0, stream,
                       x, ln_w, ln_b, Wt_all, Wtri_pad, bg, q, k, v, g, tri);
    hipLaunchKernelGGL(swizzle_triT, dim3(NH, 8, 8), dim3(64), 0, stream, tri, tswz);
    hipLaunchKernelGGL(attn_fused, dim3(NI, 2), dim3(512), 0, stream,
                       q, k, v, g, tswz, mask, Wto, bo, out);
}